// Round 7
// baseline (269.193 us; speedup 1.0000x reference)
//
#include <hip/hip_runtime.h>
#include <math.h>

#define NPIX 8192
#define DD 512
#define FF 32
#define NN 16384
#define HWS 1024
#define MARGIN 0.012f
#define NBLK 256

// ws layout (bytes); ws_size ~256MB
#define WS_KEYS64 0         // 8192*8
#define WS_KEYS32 65536     // 8192*4
#define WS_COUNTS 98304     // 16384*4
#define WS_MISC   163840    // f32[0]=loss acc; u32[16]=bar_cnt; u32[32]=bar_gen
#define WS_EN     229632    // 2 MB fp32 normalized codebook
#define WS_EH     2326784   // 1 MB tile-major bf16-h codebook (stream overread spills into WS_X: harmless)
#define WS_X      3375360   // 1 MB fp32 normalized x
#define WS_XH     4423936   // 512 KB bf16-h x fragments
#define WS_PART   4948224   // 16*8192*32*4 = 16 MB

typedef __bf16 bf16x8 __attribute__((ext_vector_type(8)));
typedef float f32x4 __attribute__((ext_vector_type(4)));
typedef unsigned int uint32x4 __attribute__((ext_vector_type(4)));

__device__ __forceinline__ unsigned short bf16_rne(float f) {
    unsigned u = __float_as_uint(f);
    u += 0x7fffu + ((u >> 16) & 1u);
    return (unsigned short)(u >> 16);
}
__device__ __forceinline__ f32x4 mfma16(bf16x8 a, bf16x8 b, f32x4 c) {
    return __builtin_amdgcn_mfma_f32_16x16x32_bf16(a, b, c, 0, 0, 0);
}
__device__ __forceinline__ unsigned mono_u32(float v) {
    unsigned u = __float_as_uint(v);
    return (u & 0x80000000u) ? ~u : (u | 0x80000000u);
}
__device__ __forceinline__ float mono_dec(unsigned u) {
    return __uint_as_float((u & 0x80000000u) ? (u ^ 0x80000000u) : ~u);
}
__device__ __forceinline__ unsigned long long packkey(float v, int n) {
    return ((unsigned long long)mono_u32(v) << 32) | (unsigned long long)(~(unsigned)n);
}

// sense-reversing grid barrier; state zeroed by vq_init each call.
// Correct for 256 co-resident blocks (1/CU guaranteed: 256 thr, 4KB LDS).
__device__ __forceinline__ void gbar(unsigned* cnt, unsigned* gen) {
    __syncthreads();
    if (threadIdx.x == 0) {
        unsigned g = __hip_atomic_load(gen, __ATOMIC_RELAXED, __HIP_MEMORY_SCOPE_AGENT);
        unsigned old = __hip_atomic_fetch_add(cnt, 1, __ATOMIC_ACQ_REL, __HIP_MEMORY_SCOPE_AGENT);
        if (old == NBLK - 1) {
            __hip_atomic_store(cnt, 0u, __ATOMIC_RELAXED, __HIP_MEMORY_SCOPE_AGENT);
            __hip_atomic_fetch_add(gen, 1, __ATOMIC_ACQ_REL, __HIP_MEMORY_SCOPE_AGENT);
        } else {
            while (__hip_atomic_load(gen, __ATOMIC_ACQUIRE, __HIP_MEMORY_SCOPE_AGENT) == g)
                __builtin_amdgcn_s_sleep(2);
        }
    }
    __syncthreads();
}

__global__ __launch_bounds__(256) void vq_init(char* __restrict__ ws) {
    int i = blockIdx.x * 256 + threadIdx.x;        // 64 blocks -> 16384
    ((int*)(ws + WS_COUNTS))[i] = 0;
    if (i < 8192) {
        ((unsigned long long*)(ws + WS_KEYS64))[i] = 0ull;
        ((unsigned*)(ws + WS_KEYS32))[i] = 0u;
    }
    if (i < 64) ((unsigned*)(ws + WS_MISC))[i] = 0u;
}

__global__ __launch_bounds__(256) void vq_mono(const float* __restrict__ enc, const float* __restrict__ emb,
                                               const float* __restrict__ pw, const float* __restrict__ pbias,
                                               const float* __restrict__ ew, const float* __restrict__ eb,
                                               float* __restrict__ out, char* __restrict__ ws) {
    __shared__ float lds[1024];
    unsigned long long* keys64 = (unsigned long long*)(ws + WS_KEYS64);
    unsigned* keys32 = (unsigned*)(ws + WS_KEYS32);
    int*   counts = (int*)(ws + WS_COUNTS);
    float* misc   = (float*)(ws + WS_MISC);
    unsigned* bcnt = (unsigned*)(ws + WS_MISC) + 16;
    unsigned* bgen = (unsigned*)(ws + WS_MISC) + 32;
    float* EN     = (float*)(ws + WS_EN);
    char*  EH     = ws + WS_EH;
    float* X      = (float*)(ws + WS_X);
    char*  XH     = ws + WS_XH;
    float* part   = (float*)(ws + WS_PART);
    int bx = blockIdx.x, tid = threadIdx.x;

    // ---- P0a: proj partials (256 vblocks: 512px, 32d, 2px/thread) + codebook (64 vblocks) ----
    for (int vb = bx; vb < 320; vb += NBLK) {
        if (vb < 256) {
            int pb0 = vb & 15, ds = vb >> 4, d0 = ds * 32;
            for (int i = tid; i < 1024; i += 256) {
                int dl = i >> 5, f = i & 31;
                lds[dl * 32 + f] = pw[f * DD + d0 + dl];   // transpose folded into stage
            }
            __syncthreads();
            int px0 = pb0 * 512 + tid;                      // px1 = px0+256, same image
            int b = px0 >> 10, hw = px0 & 1023;
            const float* ep = enc + (size_t)b * DD * HWS + (size_t)d0 * HWS + hw;
            float acc0[FF], acc1[FF];
#pragma unroll
            for (int f = 0; f < FF; f++) { acc0[f] = 0.f; acc1[f] = 0.f; }
            float ev0[4], ev1[4];
#pragma unroll
            for (int j = 0; j < 4; j++) { ev0[j] = ep[(size_t)j * HWS]; ev1[j] = ep[(size_t)j * HWS + 256]; }
#pragma unroll
            for (int g = 0; g < 8; g++) {
                float nv0[4], nv1[4];
                if (g < 7) {
#pragma unroll
                    for (int j = 0; j < 4; j++) {
                        nv0[j] = ep[(size_t)(g * 4 + 4 + j) * HWS];
                        nv1[j] = ep[(size_t)(g * 4 + 4 + j) * HWS + 256];
                    }
                }
#pragma unroll
                for (int j = 0; j < 4; j++) {
                    const float4* w4 = (const float4*)&lds[(g * 4 + j) * 32];
#pragma unroll
                    for (int q = 0; q < 8; q++) {
                        float4 w = w4[q];
                        acc0[q * 4 + 0] = fmaf(ev0[j], w.x, acc0[q * 4 + 0]);
                        acc0[q * 4 + 1] = fmaf(ev0[j], w.y, acc0[q * 4 + 1]);
                        acc0[q * 4 + 2] = fmaf(ev0[j], w.z, acc0[q * 4 + 2]);
                        acc0[q * 4 + 3] = fmaf(ev0[j], w.w, acc0[q * 4 + 3]);
                        acc1[q * 4 + 0] = fmaf(ev1[j], w.x, acc1[q * 4 + 0]);
                        acc1[q * 4 + 1] = fmaf(ev1[j], w.y, acc1[q * 4 + 1]);
                        acc1[q * 4 + 2] = fmaf(ev1[j], w.z, acc1[q * 4 + 2]);
                        acc1[q * 4 + 3] = fmaf(ev1[j], w.w, acc1[q * 4 + 3]);
                    }
                }
                if (g < 7) {
#pragma unroll
                    for (int j = 0; j < 4; j++) { ev0[j] = nv0[j]; ev1[j] = nv1[j]; }
                }
            }
            float4* o0 = (float4*)(part + ((size_t)ds * NPIX + px0) * FF);
            float4* o1 = (float4*)(part + ((size_t)ds * NPIX + px0 + 256) * FF);
#pragma unroll
            for (int q = 0; q < 8; q++) {
                o0[q] = make_float4(acc0[q * 4], acc0[q * 4 + 1], acc0[q * 4 + 2], acc0[q * 4 + 3]);
                o1[q] = make_float4(acc1[q * 4], acc1[q * 4 + 1], acc1[q * 4 + 2], acc1[q * 4 + 3]);
            }
            __syncthreads();
        } else {
            int i = (vb - 256) * 256 + tid;   // 0..16383: codebook row
            const float4* r = (const float4*)(emb + (size_t)i * FF);
            float e[FF];
            float s = 0.f;
#pragma unroll
            for (int q = 0; q < 8; q++) {
                float4 v = r[q];
                e[q * 4] = v.x; e[q * 4 + 1] = v.y; e[q * 4 + 2] = v.z; e[q * 4 + 3] = v.w;
                s += v.x * v.x + v.y * v.y + v.z * v.z + v.w * v.w;
            }
            float m = fmaxf(sqrtf(s), 1e-6f);
#pragma unroll
            for (int f = 0; f < FF; f++) e[f] = e[f] / m;
            float4* o = (float4*)(EN + (size_t)i * FF);
#pragma unroll
            for (int q = 0; q < 8; q++)
                o[q] = make_float4(e[q * 4], e[q * 4 + 1], e[q * 4 + 2], e[q * 4 + 3]);
            int g = i >> 4, rl = i & 15;
#pragma unroll
            for (int kg = 0; kg < 4; kg++) {
                unsigned hw_[4];
#pragma unroll
                for (int w = 0; w < 4; w++) {
                    unsigned short h0 = bf16_rne(e[kg * 8 + w * 2]);
                    unsigned short h1 = bf16_rne(e[kg * 8 + w * 2 + 1]);
                    hw_[w] = (unsigned)h0 | ((unsigned)h1 << 16);
                }
                uint32x4 th = {hw_[0], hw_[1], hw_[2], hw_[3]};
                *(uint32x4*)(EH + (size_t)g * 1024 + (kg * 16 + rl) * 16) = th;
            }
        }
    }
    gbar(bcnt, bgen);

    // ---- P0b: finish x (8 threads/pixel, 4 ch each; R4-proven body) ----
    {
        int t = bx * 256 + tid;
        int p = t >> 3, q = t & 7;
        float ax = 0.f, ay = 0.f, az = 0.f, aw = 0.f;
        for (int sg = 0; sg < 16; sg++) {
            float4 v = *(const float4*)(part + ((size_t)sg * NPIX + p) * FF + q * 4);
            ax += v.x; ay += v.y; az += v.z; aw += v.w;
        }
        float4 bq = *(const float4*)(pbias + q * 4);
        ax += bq.x; ay += bq.y; az += bq.z; aw += bq.w;
        float ss = ax * ax + ay * ay + az * az + aw * aw;
        ss += __shfl_xor(ss, 1);
        ss += __shfl_xor(ss, 2);
        ss += __shfl_xor(ss, 4);
        float m = fmaxf(sqrtf(ss), 1e-6f);
        ax /= m; ay /= m; az /= m; aw /= m;
        *(float4*)(X + (size_t)p * FF + q * 4) = make_float4(ax, ay, az, aw);
        unsigned h0 = (unsigned)bf16_rne(ax) | ((unsigned)bf16_rne(ay) << 16);
        unsigned h1 = (unsigned)bf16_rne(az) | ((unsigned)bf16_rne(aw) << 16);
        *(uint2*)(XH + (size_t)p * 64 + q * 8) = make_uint2(h0, h1);
    }
    gbar(bcnt, bgen);

    // ---- P2: approx argmax (h.h MFMA, paired tiles -> v_max3) -> keys32 ----
    for (int k = 0; k < 4; k++) {
        int vb = bx * 4 + k;
        int lane = tid & 63, wv = tid >> 6, rl = lane & 15, kg = lane >> 4;
        int mblk = vb & 31, nblk = vb >> 5;
        int wavebase = mblk * 256 + wv * 64;
        const uint32x4* XHp = (const uint32x4*)XH;
        bf16x8 ah[4];
#pragma unroll
        for (int m = 0; m < 4; m++)
            ah[m] = __builtin_bit_cast(bf16x8, XHp[(wavebase + m * 16 + rl) * 4 + kg]);
        const char* ebp = EH + (size_t)nblk * 32768 + lane * 16;
        float bv[16];
#pragma unroll
        for (int j = 0; j < 16; j++) bv[j] = -3.0e38f;
        uint32x4 s0 = *(const uint32x4*)(ebp);
        uint32x4 s1 = *(const uint32x4*)(ebp + 1024);
        uint32x4 s2 = *(const uint32x4*)(ebp + 2048);
        uint32x4 s3 = *(const uint32x4*)(ebp + 3072);
        for (int t = 0; t < 32; t += 2) {
            uint32x4 n0 = *(const uint32x4*)(ebp + (t + 4) * 1024);   // overread <=4KB: harmless
            uint32x4 n1 = *(const uint32x4*)(ebp + (t + 5) * 1024);
            bf16x8 bhA = __builtin_bit_cast(bf16x8, s0);
            bf16x8 bhB = __builtin_bit_cast(bf16x8, s1);
            f32x4 z = {0.f, 0.f, 0.f, 0.f};
            f32x4 a0 = mfma16(ah[0], bhA, z), a1 = mfma16(ah[1], bhA, z);
            f32x4 a2 = mfma16(ah[2], bhA, z), a3 = mfma16(ah[3], bhA, z);
            f32x4 b0 = mfma16(ah[0], bhB, z), b1 = mfma16(ah[1], bhB, z);
            f32x4 b2 = mfma16(ah[2], bhB, z), b3 = mfma16(ah[3], bhB, z);
#pragma unroll
            for (int i = 0; i < 4; i++) {
                bv[i]      = fmaxf(fmaxf(a0[i], b0[i]), bv[i]);
                bv[4 + i]  = fmaxf(fmaxf(a1[i], b1[i]), bv[4 + i]);
                bv[8 + i]  = fmaxf(fmaxf(a2[i], b2[i]), bv[8 + i]);
                bv[12 + i] = fmaxf(fmaxf(a3[i], b3[i]), bv[12 + i]);
            }
            s0 = s2; s1 = s3; s2 = n0; s3 = n1;
        }
#pragma unroll
        for (int st = 1; st < 16; st <<= 1)
#pragma unroll
            for (int j = 0; j < 16; j++) bv[j] = fmaxf(bv[j], __shfl_xor(bv[j], st));
        if (rl == 0) {
#pragma unroll
            for (int j = 0; j < 16; j++)
                atomicMax(keys32 + wavebase + (j >> 2) * 16 + kg * 4 + (j & 3), mono_u32(bv[j]));
        }
    }
    gbar(bcnt, bgen);

    // ---- P3: exact re-scan, accumulator seeded with C=-thr (candidate = c>=0) ----
    for (int k = 0; k < 4; k++) {
        int vb = bx * 4 + k;
        int lane = tid & 63, wv = tid >> 6, rl = lane & 15, kg = lane >> 4;
        int mblk = vb & 31, nblk = vb >> 5;
        int wavebase = mblk * 256 + wv * 64;
        const uint32x4* XHp = (const uint32x4*)XH;
        bf16x8 ah[4];
#pragma unroll
        for (int m = 0; m < 4; m++)
            ah[m] = __builtin_bit_cast(bf16x8, XHp[(wavebase + m * 16 + rl) * 4 + kg]);
        float nt[16];
#pragma unroll
        for (int j = 0; j < 16; j++)
            nt[j] = MARGIN - mono_dec(keys32[wavebase + (j >> 2) * 16 + kg * 4 + (j & 3)]);
        f32x4 ci0 = {nt[0], nt[1], nt[2], nt[3]};
        f32x4 ci1 = {nt[4], nt[5], nt[6], nt[7]};
        f32x4 ci2 = {nt[8], nt[9], nt[10], nt[11]};
        f32x4 ci3 = {nt[12], nt[13], nt[14], nt[15]};
        const char* ebp = EH + (size_t)nblk * 32768 + lane * 16;
        uint32x4 s0 = *(const uint32x4*)(ebp);
        uint32x4 s1 = *(const uint32x4*)(ebp + 1024);
        uint32x4 s2 = *(const uint32x4*)(ebp + 2048);
        uint32x4 s3 = *(const uint32x4*)(ebp + 3072);
        for (int t = 0; t < 32; t += 2) {
            uint32x4 n0 = *(const uint32x4*)(ebp + (t + 4) * 1024);
            uint32x4 n1 = *(const uint32x4*)(ebp + (t + 5) * 1024);
#pragma unroll
            for (int half = 0; half < 2; half++) {
                bf16x8 bh = __builtin_bit_cast(bf16x8, half ? s1 : s0);
                int T = t + half;
                f32x4 c0 = mfma16(ah[0], bh, ci0);
                f32x4 c1 = mfma16(ah[1], bh, ci1);
                f32x4 c2 = mfma16(ah[2], bh, ci2);
                f32x4 c3 = mfma16(ah[3], bh, ci3);
                float dm = fmaxf(fmaxf(fmaxf(fmaxf(c0[0], c0[1]), fmaxf(c0[2], c0[3])),
                                       fmaxf(fmaxf(c1[0], c1[1]), fmaxf(c1[2], c1[3]))),
                                 fmaxf(fmaxf(fmaxf(c2[0], c2[1]), fmaxf(c2[2], c2[3])),
                                       fmaxf(fmaxf(c3[0], c3[1]), fmaxf(c3[2], c3[3]))));
                if (dm >= 0.f) {
                    float av[16];
#pragma unroll
                    for (int i = 0; i < 4; i++) {
                        av[i] = c0[i]; av[4 + i] = c1[i];
                        av[8 + i] = c2[i]; av[12 + i] = c3[i];
                    }
#pragma unroll
                    for (int j = 0; j < 16; j++) {
                        if (av[j] >= 0.f) {
                            int p = wavebase + (j >> 2) * 16 + kg * 4 + (j & 3);
                            int n = nblk * 512 + T * 16 + rl;
                            const float4* xr = (const float4*)(X + (size_t)p * FF);
                            const float4* er = (const float4*)(EN + (size_t)n * FF);
                            float a0 = 0.f, a1 = 0.f, a2 = 0.f, a3 = 0.f;
#pragma unroll
                            for (int q = 0; q < 8; q++) {
                                float4 xv = xr[q], ev = er[q];
                                a0 = fmaf(xv.x, ev.x, a0); a1 = fmaf(xv.y, ev.y, a1);
                                a2 = fmaf(xv.z, ev.z, a2); a3 = fmaf(xv.w, ev.w, a3);
                            }
                            float v = (a0 + a1) + (a2 + a3);
                            atomicMax(keys64 + p, packkey(v, n));
                        }
                    }
                }
            }
            s0 = s2; s1 = s3; s2 = n0; s3 = n1;
        }
    }
    gbar(bcnt, bgen);

    // ---- P4: expand GEMM + closest/hist/loss (R4-proven body) ----
    for (int k = 0; k < 4; k++) {
        int vb = bx * 4 + k;
        int lane = tid & 63, wv = tid >> 6;
        int pb2 = vb & 127, dg = vb >> 7;
        int p = pb2 * 64 + lane;
        unsigned n = ~(unsigned)(keys64[p]);
        float lat[FF];
        const float4* l4 = (const float4*)(EN + (size_t)n * FF);
#pragma unroll
        for (int q = 0; q < 8; q++) {
            float4 v = l4[q];
            lat[q * 4] = v.x; lat[q * 4 + 1] = v.y; lat[q * 4 + 2] = v.z; lat[q * 4 + 3] = v.w;
        }
        if (dg == 0 && wv == 0) {
            out[4194304 + p] = (float)n;
            atomicAdd(counts + n, 1);
            const float4* xr = (const float4*)(X + (size_t)p * FF);
            float s = 0.f;
#pragma unroll
            for (int q = 0; q < 8; q++) {
                float4 xv = xr[q];
                float dx = xv.x - lat[q * 4], dy = xv.y - lat[q * 4 + 1];
                float dz = xv.z - lat[q * 4 + 2], dw = xv.w - lat[q * 4 + 3];
                s += dx * dx + dy * dy + dz * dz + dw * dw;
            }
            for (int off = 32; off > 0; off >>= 1) s += __shfl_down(s, off);
            if (lane == 0) atomicAdd(misc, s);
        }
        int b = p >> 10, hw = p & 1023;
        float* op = out + (size_t)b * DD * HWS + hw;
        int d0 = dg * 64 + wv * 16;
        for (int i = 0; i < 16; i++) {
            int d = d0 + i;
            const float4* w4 = (const float4*)(ew + (size_t)d * FF);
            float4 w0 = w4[0], w1 = w4[1], w2 = w4[2], w3 = w4[3];
            float4 w5 = w4[4], w6 = w4[5], w7 = w4[6], w8 = w4[7];
            float a0 = fmaf(lat[0], w0.x, eb[d]);
            float a1 = lat[1] * w0.y;
            float a2 = lat[2] * w0.z;
            float a3 = lat[3] * w0.w;
            a0 = fmaf(lat[4],  w1.x, a0); a1 = fmaf(lat[5],  w1.y, a1); a2 = fmaf(lat[6],  w1.z, a2); a3 = fmaf(lat[7],  w1.w, a3);
            a0 = fmaf(lat[8],  w2.x, a0); a1 = fmaf(lat[9],  w2.y, a1); a2 = fmaf(lat[10], w2.z, a2); a3 = fmaf(lat[11], w2.w, a3);
            a0 = fmaf(lat[12], w3.x, a0); a1 = fmaf(lat[13], w3.y, a1); a2 = fmaf(lat[14], w3.z, a2); a3 = fmaf(lat[15], w3.w, a3);
            a0 = fmaf(lat[16], w5.x, a0); a1 = fmaf(lat[17], w5.y, a1); a2 = fmaf(lat[18], w5.z, a2); a3 = fmaf(lat[19], w5.w, a3);
            a0 = fmaf(lat[20], w6.x, a0); a1 = fmaf(lat[21], w6.y, a1); a2 = fmaf(lat[22], w6.z, a2); a3 = fmaf(lat[23], w6.w, a3);
            a0 = fmaf(lat[24], w7.x, a0); a1 = fmaf(lat[25], w7.y, a1); a2 = fmaf(lat[26], w7.z, a2); a3 = fmaf(lat[27], w7.w, a3);
            a0 = fmaf(lat[28], w8.x, a0); a1 = fmaf(lat[29], w8.y, a1); a2 = fmaf(lat[30], w8.z, a2); a3 = fmaf(lat[31], w8.w, a3);
            op[(size_t)d * HWS] = (a0 + a1) + (a2 + a3);
        }
    }
    gbar(bcnt, bgen);

    // ---- P5: perplexity + finalize (block 0) ----
    if (bx == 0) {
        float s = 0.f;
#pragma unroll
        for (int r = 0; r < 64; r++) {
            float u = (float)counts[tid + r * 256] * (1.0f / 8192.0f);
            s += u * logf(u + 1e-6f);
        }
        for (int off = 32; off > 0; off >>= 1) s += __shfl_down(s, off);
        if ((tid & 63) == 0) lds[tid >> 6] = s;
        __syncthreads();
        if (tid == 0) {
            float t = lds[0] + lds[1] + lds[2] + lds[3];
            out[4194304 + NPIX]     = misc[0] * (1.0f / 262144.0f);   // loss: mean over B*F*H*W
            out[4194304 + NPIX + 1] = expf(-t);                       // perplexity
        }
    }
}

extern "C" void kernel_launch(void* const* d_in, const int* in_sizes, int n_in,
                              void* d_out, int out_size, void* d_ws, size_t ws_size,
                              hipStream_t stream) {
    const float* enc   = (const float*)d_in[0];
    const float* emb   = (const float*)d_in[1];
    const float* pw    = (const float*)d_in[2];
    const float* pbias = (const float*)d_in[3];
    const float* ew    = (const float*)d_in[4];
    const float* eb    = (const float*)d_in[5];
    float* out = (float*)d_out;
    char* ws = (char*)d_ws;

    vq_init<<<64, 256, 0, stream>>>(ws);
    vq_mono<<<NBLK, 256, 0, stream>>>(enc, emb, pw, pbias, ew, eb, out, ws);
}